// Round 1
// 253.666 us; speedup vs baseline: 2.5516x; 2.5516x over previous
//
#include <hip/hip_runtime.h>
#include <hip/hip_fp16.h>

// Problem constants
#define BB 16
#define NN 1024
#define MAX_ITER 100

constexpr float EPS_F    = 0.1f;
constexpr float INV_EPS  = 10.0f;
constexpr float MU_P     = 0.0009765625f + 1e-8f;      // 1/1024 + 1e-8  (== nu)
constexpr float LOG_MU   = -6.9314615656526045f;       // log(MU_P)
constexpr float THRESH_B = 1.6f;                        // THRESH(0.1) * B(16)

#define SCOPE_AGENT __HIP_MEMORY_SCOPE_AGENT

// Coherent (agent-scope) primitives. Reads: relaxed atomic load (bypasses
// stale L1/L2 copies — same mechanism ROCm grid.sync spins on). Writes:
// atomicExch RMW (executes at the coherence point; unambiguously visible to
// subsequent coherent reads). No agent-scope FENCES are used in the hot loop,
// so the per-XCD L2 is never invalidated and the E tile stays resident.
__device__ __forceinline__ float coh_loadf(float* p) {
    return __hip_atomic_load(p, __ATOMIC_RELAXED, SCOPE_AGENT);
}
__device__ __forceinline__ int coh_loadi(int* p) {
    return __hip_atomic_load(p, __ATOMIC_RELAXED, SCOPE_AGENT);
}
__device__ __forceinline__ void coh_storef(float* p, float v) {
    atomicExch(p, v);
}

// 16-block per-batch barrier, sequence-numbered (target = 16 * seq).
// __syncthreads drains vmcnt before s_barrier (compiler-guaranteed), so all
// of this block's RMWs are durable at the coherence point before the arrival
// add. Spin uses s_sleep to stay polite on the L2 atomic path.
__device__ __forceinline__ void batch_sync(int* cnt, int target) {
    __syncthreads();
    if (threadIdx.x == 0) {
        __threadfence_block();
        atomicAdd(cnt, 1);
        while (coh_loadi(cnt) < target) __builtin_amdgcn_s_sleep(1);
        __threadfence_block();
    }
    __syncthreads();
}

// ---------------------------------------------------------------------------
// K1: E = exp(-C/eps) in fp16; init u=0, wv=1; zero sync/err counters.
// grid 16384 x 256 : 4 E-elements per thread.
__global__ __launch_bounds__(256) void prep_kernel(
    const float* __restrict__ C, __half* __restrict__ E,
    float* __restrict__ u, float* __restrict__ wv,
    float* __restrict__ errB, float* __restrict__ errTot,
    int* __restrict__ errCnt, int* __restrict__ bsync)
{
    size_t gid = (size_t)blockIdx.x * 256 + threadIdx.x;   // 0..4194303
    float4 c = ((const float4*)C)[gid];
    __half2* E2 = (__half2*)E;
    E2[2*gid]   = __floats2half2_rn(__expf(-INV_EPS*c.x), __expf(-INV_EPS*c.y));
    E2[2*gid+1] = __floats2half2_rn(__expf(-INV_EPS*c.z), __expf(-INV_EPS*c.w));
    if (gid < BB*NN) { u[gid] = 0.f; wv[gid] = 1.f; }
    if (gid < 6400) errB[gid] = 0.f;          // stride-4 padded [it][b]
    if (gid < 400)  { errTot[gid] = 0.f; errCnt[gid] = 0; }   // stride-4 [it]
    if (gid < 256)  bsync[gid] = 0;           // stride-16 [b]
}

// ---------------------------------------------------------------------------
// K2: Sinkhorn loop. 256 blocks x 1024 threads (1 block/CU, 16 waves).
// Block owns 64 rows of one batch for the u-update AND produces column
// partials for all 1024 columns from the SAME vectorized E loads (fused:
// after the butterfly reduce every lane holds s, so wu=MU_P/s is in-register).
// Cross-block work per iteration: Tpart exchange + wv broadcast, coordinated
// by two 16-block per-batch barriers; the global early-break test is a
// one-sided spin on a batch-completion counter (no grid-wide barrier).
__global__ __launch_bounds__(1024, 4) void sink_iter(
    const __half* __restrict__ E, float* __restrict__ u, float* __restrict__ v,
    float* __restrict__ wv, float* __restrict__ Tpart,
    float* __restrict__ errB, float* __restrict__ errTot,
    int* __restrict__ errCnt, int* __restrict__ bsync)
{
    const int tid  = threadIdx.x;
    const int lane = tid & 63;
    const int wav  = tid >> 6;            // 0..15
    const int blk  = blockIdx.x;          // 0..255
    // XCD-grouped mapping (assumes blk%8 ~ XCD; perf-only, any bijection is
    // correct): batches 2x,2x+1 -> XCD x, so each batch's 16 blocks share L2.
    const int slot = blk >> 3;            // 0..31
    const int b    = ((blk & 7) << 1) | (slot >> 4);
    const int sub  = slot & 15;

    const __half* Eb = E + ((size_t)b << 20);
    float* ub  = u  + (b << 10);
    float* vb  = v  + (b << 10);
    float* wvb = wv + (b << 10);
    float* Tb  = Tpart + (b << 14);       // [16][1024] per batch
    int*   bs  = bsync + (b << 4);

    __shared__ float part[16][1028];      // wave col-partials (XOR-swizzled)
    __shared__ float wv_lds[1024];        // staged wv (XOR-swizzled)
    __shared__ float werr[16];
    __shared__ float errv_s;

    for (int it = 0; it < MAX_ITER; ++it) {
        // ---- stage wv -> LDS (1 coherent load/thread, coalesced) ----------
        // Swizzle: phys(c) = c ^ (((c>>4)&7)<<2) — makes the later 64B-stride
        // float4 reads hit all 32 banks (else 32-way conflict).
        wv_lds[tid ^ (((tid >> 4) & 7) << 2)] = coh_loadf(&wvb[tid]);
        __syncthreads();

        float wf[16];
        #pragma unroll
        for (int j = 0; j < 4; ++j) {
            int idx = ((lane << 4) | (j << 2)) ^ ((lane & 7) << 2);
            float4 t4 = *(const float4*)&wv_lds[idx];
            wf[4*j+0] = t4.x; wf[4*j+1] = t4.y; wf[4*j+2] = t4.z; wf[4*j+3] = t4.w;
        }

        // ---- fused pass: u-update + column partials (one E read) ----------
        float acc[16];
        #pragma unroll
        for (int k = 0; k < 16; ++k) acc[k] = 0.f;
        float derr = 0.f;
        #pragma unroll
        for (int r = 0; r < 4; ++r) {
            const int row = (sub << 6) + (wav << 2) + r;
            const uint4* Ep = (const uint4*)(Eb + ((size_t)row << 10));
            union { uint4 q; __half2 h[4]; } a0, a1;
            a0.q = Ep[2*lane];
            a1.q = Ep[2*lane + 1];
            float f0[8], f1[8];
            #pragma unroll
            for (int k = 0; k < 4; ++k) {
                float2 fa = __half22float2(a0.h[k]);
                float2 fb = __half22float2(a1.h[k]);
                f0[2*k] = fa.x; f0[2*k+1] = fa.y;
                f1[2*k] = fb.x; f1[2*k+1] = fb.y;
            }
            float s = 0.f;
            #pragma unroll
            for (int k = 0; k < 8; ++k) s = fmaf(f0[k], wf[k], s);
            #pragma unroll
            for (int k = 0; k < 8; ++k) s = fmaf(f1[k], wf[8+k], s);
            #pragma unroll
            for (int off = 32; off >= 1; off >>= 1) s += __shfl_xor(s, off);
            float un = EPS_F * (LOG_MU - __logf(s));
            derr += fabsf(un - ub[row]);          // old u read before store
            if (lane == 0) ub[row] = un;
            float wuv = MU_P / s;                  // exp(u_new/eps), all lanes
            #pragma unroll
            for (int k = 0; k < 8; ++k) acc[k]   = fmaf(f0[k], wuv, acc[k]);
            #pragma unroll
            for (int k = 0; k < 8; ++k) acc[8+k] = fmaf(f1[k], wuv, acc[8+k]);
        }
        if (lane == 0) werr[wav] = derr;

        // wave partials -> LDS (swizzled float4: 8-way = conflict-free b128)
        #pragma unroll
        for (int j = 0; j < 4; ++j) {
            int idx = ((lane << 4) | (j << 2)) ^ ((lane & 7) << 2);
            *(float4*)&part[wav][idx] =
                make_float4(acc[4*j], acc[4*j+1], acc[4*j+2], acc[4*j+3]);
        }
        __syncthreads();

        // cross-wave reduce (deterministic, rows ascending) -> Tpart[b][sub]
        {
            int pidx = tid ^ (((tid >> 4) & 7) << 2);
            float ts = 0.f;
            #pragma unroll
            for (int w = 0; w < 16; ++w) ts += part[w][pidx];
            coh_storef(&Tb[(sub << 10) + tid], ts);
        }
        // block err -> per-batch err (RMW)
        if (wav == 0) {
            float e = (lane < 16) ? werr[lane] : 0.f;
            #pragma unroll
            for (int off = 8; off >= 1; off >>= 1) e += __shfl_xor(e, off);
            if (lane == 0) atomicAdd(&errB[(((it << 4) + b) << 2)], e);
        }

        batch_sync(bs, (it << 5) + 16);

        // batch b's err contribution is now complete: publish to global err
        if (sub == 0 && tid == 0) {
            float eb = coh_loadf(&errB[(((it << 4) + b) << 2)]);
            atomicAdd(&errTot[it << 2], eb);
            __threadfence_block();                 // order errTot before errCnt
            atomicAdd(&errCnt[it << 2], 1);
        }

        // ---- v-update: combine 16 block-partials for our 64 columns -------
        {
            const int s16 = tid >> 6;
            const int cl  = tid & 63;
            float pv = coh_loadf(&Tb[(s16 << 10) + (sub << 6) + cl]);
            part[s16][cl] = pv;                    // reuse LDS (dead data)
            __syncthreads();
            if (tid < 64) {
                float t = 0.f;
                #pragma unroll
                for (int w = 0; w < 16; ++w) t += part[w][tid];
                const int col = (sub << 6) + tid;
                vb[col] = EPS_F * (LOG_MU - __logf(t));
                coh_storef(&wvb[col], MU_P / t);
            }
        }

        batch_sync(bs, (it << 5) + 32);

        // ---- break check: one-sided wait for all 16 batch contributions ---
        if (tid == 0) {
            while (coh_loadi(&errCnt[it << 2]) < 16) __builtin_amdgcn_s_sleep(1);
            errv_s = coh_loadf(&errTot[it << 2]);
        }
        __syncthreads();
        if (errv_s < THRESH_B) break;              // uniform across the grid
    }
}

// ---------------------------------------------------------------------------
// K3: pi = exp((u_i + v_j - C_ij)/eps), copy C, per-block partial cost.
__global__ __launch_bounds__(256) void epilogue(
    const float* __restrict__ C, const float* __restrict__ u, const float* __restrict__ v,
    float* __restrict__ outPi, float* __restrict__ outC, float* __restrict__ part)
{
    int blk = blockIdx.x;
    int b = blk >> 10;
    int i = blk & 1023;
    size_t base = (size_t)blk << 10;
    const float4* C4 = (const float4*)(C + base);
    const float4* v4 = (const float4*)(v + ((size_t)b << 10));
    float4* P4 = (float4*)(outPi + base);
    float4* O4 = (float4*)(outC + base);
    float ui = u[(b << 10) + i];
    int t = threadIdx.x;
    float4 c = C4[t];
    float4 vv = v4[t];
    float4 p;
    p.x = __expf((ui + vv.x - c.x) * INV_EPS);
    p.y = __expf((ui + vv.y - c.y) * INV_EPS);
    p.z = __expf((ui + vv.z - c.z) * INV_EPS);
    p.w = __expf((ui + vv.w - c.w) * INV_EPS);
    P4[t] = p;
    O4[t] = c;
    float cp = p.x*c.x + p.y*c.y + p.z*c.z + p.w*c.w;
    #pragma unroll
    for (int off = 32; off >= 1; off >>= 1) cp += __shfl_xor(cp, off);
    __shared__ float ps[4];
    if ((t & 63) == 0) ps[t >> 6] = cp;
    __syncthreads();
    if (t == 0) part[blk] = ps[0] + ps[1] + ps[2] + ps[3];
}

// K4: reduce 1024 partials per batch -> cost[16].
__global__ __launch_bounds__(1024) void cost_reduce(
    const float* __restrict__ part, float* __restrict__ outCost)
{
    int b = blockIdx.x;
    int t = threadIdx.x;
    float s = part[(b << 10) + t];
    #pragma unroll
    for (int off = 32; off >= 1; off >>= 1) s += __shfl_xor(s, off);
    __shared__ float ps[16];
    if ((t & 63) == 0) ps[t >> 6] = s;
    __syncthreads();
    if (t < 64) {
        float e = (t < 16) ? ps[t] : 0.f;
        #pragma unroll
        for (int off = 8; off >= 1; off >>= 1) e += __shfl_xor(e, off);
        if (t == 0) outCost[b] = e;
    }
}

// ---------------------------------------------------------------------------
extern "C" void kernel_launch(void* const* d_in, const int* in_sizes, int n_in,
                              void* d_out, int out_size, void* d_ws, size_t ws_size,
                              hipStream_t stream)
{
    const float* C = (const float*)d_in[2];   // x,y unused (shapes only)
    float* out = (float*)d_out;

    // ws layout (~33.85 MB, under the previously-proven 33.9 MB footprint):
    char* ws = (char*)d_ws;
    __half* E     = (__half*)ws;                      // 16M fp16 = 32 MB
    float* u      = (float*)(ws + (size_t)33554432);  // 16384
    float* v      = u + 16384;                        // 16384
    float* wv     = v + 16384;                        // 16384
    float* part   = wv + 16384;                       // 16384 (epilogue partials)
    float* errB   = part + 16384;                     // 6400  (stride-4 [it][b])
    float* errTot = errB + 6400;                      // 400   (stride-4 [it])
    int*   errCnt = (int*)(errTot + 400);             // 400
    int*   bsync  = errCnt + 400;                     // 256   (stride-16 [b])

    float* outPi = out + 16;
    float* outC  = out + 16 + (size_t)16777216;
    // Tpart scratch (16 batches x 16 blocks x 1024 f32 = 1 MB) lives in the
    // pi output region: sink_iter finishes before epilogue overwrites it.
    float* Tpart = outPi;

    prep_kernel<<<16384, 256, 0, stream>>>(C, E, u, wv, errB, errTot, errCnt, bsync);

    void* args[] = { (void*)&E, (void*)&u, (void*)&v, (void*)&wv, (void*)&Tpart,
                     (void*)&errB, (void*)&errTot, (void*)&errCnt, (void*)&bsync };
    hipLaunchCooperativeKernel((void*)sink_iter, dim3(256), dim3(1024),
                               args, 0, stream);

    epilogue<<<16384, 256, 0, stream>>>(C, u, v, outPi, outC, part);
    cost_reduce<<<16, 1024, 0, stream>>>(part, out);
}